// Round 23
// baseline (6585.467 us; speedup 1.0000x reference)
//
#include <hip/hip_runtime.h>
#include <stdint.h>

// BiLSTM on MI355X — R23 FINAL (= R21, the proven fastest configuration).
// 13.79 ms -> 6.57 ms over the session. Structure:
//   k_init/k_wcast/k_xcast: setup (reset masks; W->bf16 [n][k]; x->bf16 TM).
//   k_rec (fused, 256 WGs x 512 thr, 1 WG/CU):
//     blocks 0-31   : persistent recurrence. WG (dir,p) owns h-cols
//                     [32p,32p+32) of all 4 gates; W_h panel in LDS
//                     (XOR-swizzled); per-step cross-WG h broadcast via
//                     agent-scope relaxed write-through stores + vmcnt
//                     drain + per-WG 64B-strided tag; consumer: wave-0
//                     poll + one acquire-invalidate + plain coalesced
//                     cached h loads (the R13 breakthrough).
//     blocks 32-255 : Z = x@Wx+b GEMM workers overlapped with the
//                     recurrence (grid-stride tiles, bf16 Z write-through,
//                     zready flags gate the consumers).
// Per-step cost ~6.4us is a cross-CU sync-latency floor (HBM 2.4%,
// MFMA 1.7% — not a memory/compute roofline): verified not-clock (R22),
// not-W-residency (R11/R12), not-poll-structure (R15), not-load-issue
// (R16/R17), not-bank-conflicts (R18); intra-XCD L2-scope handoff
// correctness-refuted twice on HW (R14/R19).
// Backward dir: hk.ResetCore — state zeroed before flipped step t when
// t <= L - len[b]. OUTPUT IS FP32.

typedef __attribute__((ext_vector_type(8))) short  short8;
typedef __attribute__((ext_vector_type(4))) float  floatx4;

#define LSEQ 1024
#define NB   32
#define DD   512
#define HH   512
#define NG   2048

// ---- workspace layout (bytes) ----
#define WX_OFF  0ul                           // bf16 [dir][n][k]   4 MiB
#define WH_OFF  (4ul<<20)                     // bf16 [dir][n][k]   4 MiB
#define X_OFF   (8ul<<20)                     // bf16 [t][b][d]    32 MiB (unflipped)
#define H_OFF   (40ul<<20)                    // bf16 h ping-pong [dir][par][b][h] 256 KiB
#define RST_OFF ((40ul<<20)+(384ul<<10))      // u32 [1024]
#define TAG_OFF ((40ul<<20)+(388ul<<10))      // int [2][16][16] tags, 64B-strided
#define ZR_OFF  ((40ul<<20)+(392ul<<10))      // int [2][256][16] zready (32 KiB)
#define Z_OFF   (41ul<<20)                    // bf16 [dir][step][b][n] 256 MiB
#define ZB_BYTES (2ul*LSEQ*NB*NG*2)
#define WS_NEED (Z_OFF + ZB_BYTES)            // ~297 MiB

__device__ inline uint16_t f2bf(float f) {
  uint32_t u = __float_as_uint(f);
  u += 0x7fff + ((u >> 16) & 1);              // RNE
  return (uint16_t)(u >> 16);
}
__device__ inline float fsigm(float x) { return 1.0f / (1.0f + __expf(-x)); }
__device__ inline float ftanh(float x) { return 1.0f - 2.0f / (__expf(2.0f * x) + 1.0f); }

// write-through (MALL-visible) bf16 store for Z (value in low 16 bits)
__device__ inline void zstore_wt(uint16_t* p, uint32_t v) {
  asm volatile("global_store_short %0, %1, off sc0 sc1"
               :: "v"(p), "v"(v) : "memory");
}
__device__ inline float2 zld2b(const uint16_t* p) {
  uint32_t u = *(const uint32_t*)p;
  float2 r;
  r.x = __uint_as_float((u & 0xffffu) << 16);
  r.y = __uint_as_float(u & 0xffff0000u);
  return r;
}

// ---------------- K0: init H, tags, zready, reset masks ----------------
__global__ void k_init(const int* __restrict__ len, uint32_t* __restrict__ rst,
                       int* __restrict__ tags, int* __restrict__ zr,
                       uint16_t* __restrict__ H)
{
  int tid = blockIdx.x * blockDim.x + threadIdx.x;
  int stride = gridDim.x * blockDim.x;
  for (int i = tid; i < 512; i += stride) tags[i] = 0;
  for (int i = tid; i < 2 * 256 * 16; i += stride) zr[i] = 0;
  for (int i = tid; i < 2 * 2 * NB * HH; i += stride) H[i] = 0;
  for (int t = tid; t < LSEQ; t += stride) {
    uint32_t m = 0;
    for (int b = 0; b < NB; ++b)
      m |= ((uint32_t)(t <= LSEQ - len[b])) << b;   // reset BEFORE flipped step t
    rst[t] = m;
  }
}

// ---------------- K1: W fp32 -> bf16, transpose to [n][k] ----------------
__global__ void k_wcast(const float* __restrict__ Wf, const float* __restrict__ Wb,
                        uint16_t* __restrict__ WX, uint16_t* __restrict__ WH)
{
  int tid = blockIdx.x * blockDim.x + threadIdx.x;   // [0, 2^20)
  if (tid >= 2 * 1024 * 512) return;
  int dir = tid >> 19;
  int r = tid & ((1 << 19) - 1);
  int k = r >> 9;                  // row of W (0..1023)
  int n4 = (r & 511) * 4;          // gate-col group
  const float* W = dir ? Wb : Wf;
  const float4 v = *(const float4*)(W + (size_t)k * NG + n4);
  uint16_t* dst;
  int kk;
  if (k < DD) { dst = WX + (size_t)dir * NG * DD; kk = k; }
  else        { dst = WH + (size_t)dir * NG * HH; kk = k - DD; }
  dst[(size_t)(n4 + 0) * 512 + kk] = f2bf(v.x);
  dst[(size_t)(n4 + 1) * 512 + kk] = f2bf(v.y);
  dst[(size_t)(n4 + 2) * 512 + kk] = f2bf(v.z);
  dst[(size_t)(n4 + 3) * 512 + kk] = f2bf(v.w);
}

// ---------------- K2: x fp32 -> bf16 time-major [t][b][d] ----------------
__global__ void k_xcast(const float* __restrict__ x, uint16_t* __restrict__ X)
{
  int i4 = blockIdx.x * blockDim.x + threadIdx.x;    // [0, 2^22)
  if (i4 >= (NB * LSEQ * DD) / 4) return;
  int d4 = (i4 & 127) * 4;
  int t  = (i4 >> 7) & 1023;
  int b  = i4 >> 17;
  const float4 v = *(const float4*)(x + (size_t)i4 * 4);
  uint32_t lo = (uint32_t)f2bf(v.x) | ((uint32_t)f2bf(v.y) << 16);
  uint32_t hi = (uint32_t)f2bf(v.z) | ((uint32_t)f2bf(v.w) << 16);
  uint2 u; u.x = lo; u.y = hi;
  *(uint2*)(X + ((size_t)t * NB + b) * DD + d4) = u;
}

// ---------------- K3: fused persistent kernel ----------------
// grid = 256 WGs x 512 threads, 1 WG/CU (144 KB LDS).
__global__ __launch_bounds__(512, 2) void k_rec(
    const uint16_t* __restrict__ WH, const uint16_t* __restrict__ WX,
    const uint16_t* __restrict__ X, uint16_t* __restrict__ Z,
    const float* __restrict__ bf_, const float* __restrict__ bb_,
    const uint32_t* __restrict__ rst, uint16_t* __restrict__ hbuf,
    int* __restrict__ tags, int* __restrict__ zready,
    float* __restrict__ out)
{
  __shared__ uint16_t sW[128 * 512];   // 128 KB: rec W panel / gemm tiles
  __shared__ float sG[NB * 128];       // 16 KB gate sums [b][gate*32+col]

  const int bid = blockIdx.x;
  const int tid = threadIdx.x;
  const int lane = tid & 63;
  const int wid = tid >> 6;

  if (bid >= 32) {
    // ================= GEMM worker role =================
    uint16_t* sA = sW;                  // 128x32 bf16 tile
    uint16_t* sB = sW + 128 * 32;
    const int wm = (wid >> 2) * 64;     // 2 row-halves x 4 col-quads
    const int wn = (wid & 3) * 32;

    for (int tau = bid - 32; tau < 8192; tau += 224) {
      const int mtile = tau >> 5;
      const int rem = tau & 31;
      const int dir = rem >> 4;
      const int ntile = rem & 15;

      const uint16_t* B = WX + (size_t)dir * NG * 512 + (size_t)(ntile * 128) * 512;
      const float* bias = (dir ? bb_ : bf_) + ntile * 128;

      uint4 ra, rb;
      auto load_tile = [&](int kk) {
        int row = tid >> 2, ko = (tid & 3) * 8;
        int grow = mtile * 128 + row;
        int step = grow >> 5, bb = grow & 31;
        int srow = dir ? ((1023 - step) * 32 + bb) : grow;   // flip time for bwd
        ra = *(const uint4*)(X + (size_t)srow * 512 + kk * 32 + ko);
        rb = *(const uint4*)(B + (size_t)row * 512 + kk * 32 + ko);
      };
      auto write_tile = [&]() {
        int row = tid >> 2, ko = (tid & 3) * 8;
        *(uint4*)(sA + row * 32 + ko) = ra;
        *(uint4*)(sB + row * 32 + ko) = rb;
      };

      floatx4 acc[4][2];
#pragma unroll
      for (int m = 0; m < 4; ++m)
#pragma unroll
        for (int n = 0; n < 2; ++n)
#pragma unroll
          for (int r = 0; r < 4; ++r) acc[m][n][r] = 0.f;

      load_tile(0);
      for (int kk = 0; kk < 16; ++kk) {
        __syncthreads();
        write_tile();
        __syncthreads();
        if (kk < 15) load_tile(kk + 1);
        short8 af[4], bb8[2];
#pragma unroll
        for (int m = 0; m < 4; ++m)
          af[m] = *(const short8*)(sA + (wm + m * 16 + (lane & 15)) * 32 + (lane >> 4) * 8);
#pragma unroll
        for (int n = 0; n < 2; ++n)
          bb8[n] = *(const short8*)(sB + (wn + n * 16 + (lane & 15)) * 32 + (lane >> 4) * 8);
#pragma unroll
        for (int m = 0; m < 4; ++m)
#pragma unroll
          for (int n = 0; n < 2; ++n)
            acc[m][n] = __builtin_amdgcn_mfma_f32_16x16x32_bf16(af[m], bb8[n], acc[m][n], 0, 0, 0);
      }

      uint16_t* Zo = Z + ((size_t)dir * 32768 + (size_t)mtile * 128) * 2048 + ntile * 128;
#pragma unroll
      for (int n = 0; n < 2; ++n) {
        int col = wn + n * 16 + (lane & 15);
        float bv = bias[col];
#pragma unroll
        for (int m = 0; m < 4; ++m) {
          int row0 = wm + m * 16 + (lane >> 4) * 4;
#pragma unroll
          for (int r = 0; r < 4; ++r)
            zstore_wt(Zo + (size_t)(row0 + r) * 2048 + col,
                      (uint32_t)f2bf(acc[m][n][r] + bv));
        }
      }
      asm volatile("s_waitcnt vmcnt(0)" ::: "memory");
      __syncthreads();   // all waves' Z stores drained
      if (tid == 0)
        __hip_atomic_fetch_add(zready + ((size_t)dir * 256 + mtile) * 16, 1,
                               __ATOMIC_RELAXED, __HIP_MEMORY_SCOPE_AGENT);
    }
    return;
  }

  // ================= recurrence role (R13 protocol) =================
  const int gate = wid & 3;
  const int khalf = wid >> 2;
  const int dir = bid >> 4;
  const int p = bid & 15;
  const int r0 = lane & 15;
  const int k8 = (lane >> 4) * 8;

  // stage W_h panel into LDS once (XOR-swizzled rows)
  {
    const uint16_t* Wg = WH + (size_t)dir * NG * HH;
    for (int i = tid; i < 8192; i += 512) {
      int lrow = i >> 6;
      int k16  = i & 63;
      int n = (lrow >> 5) * 512 + p * 32 + (lrow & 31);
      uint4 v = *(const uint4*)(Wg + (size_t)n * 512 + k16 * 8);
      int byte = lrow * 1024 + k16 * 16;
      *(uint4*)((char*)sW + (byte ^ ((lrow & 7) << 4))) = v;
    }
  }

  short8 zero8;
#pragma unroll
  for (int i = 0; i < 8; ++i) zero8[i] = 0;

  const int swz = (r0 & 7) << 4;
  const int wrow0 = (gate * 32 + r0) * 1024 + (khalf * 256 + k8) * 2;
  const int wrow1 = wrow0 + 16 * 1024;

  float cst0 = 0.f, cst1 = 0.f;
  const int b_e = tid >> 4;
  const int hc0 = (tid & 15) * 2;

  const uint16_t* Zb = Z + (size_t)dir * LSEQ * NB * NG + (size_t)b_e * NG + p * 32 + hc0;
  uint16_t* hb = hbuf + dir * 2 * NB * HH;
  int* tg = tags + dir * 256;
  int* myslot = tg + p * 16;
  const int* zrd = zready + (size_t)dir * 256 * 16;

  __syncthreads();   // W panel staged

  for (int t = 0; t < LSEQ; ++t) {
    const uint32_t rm = dir ? rst[t] : 0u;

    // poll: lanes 0-15 watch producer tags; lane 16 gates Z readiness
    if (wid == 0) {
      const int mt = t >> 2;
      int guard = 0;
      for (;;) {
        int ok = 1;
        if (lane < 16)
          ok = __hip_atomic_load(tg + lane * 16, __ATOMIC_RELAXED,
                                 __HIP_MEMORY_SCOPE_AGENT) >= t;
        else if (lane == 16)
          ok = __hip_atomic_load(zrd + mt * 16, __ATOMIC_RELAXED,
                                 __HIP_MEMORY_SCOPE_AGENT) >= 16;
        if (__all(ok)) break;
        __builtin_amdgcn_s_sleep(1);
        if (++guard > (1 << 15)) break;   // bounded anti-hang guard
      }
      // ONE acquire: L1/L2 invalidate so plain cached h/Z loads are fresh
      if (lane < 16)
        (void)__hip_atomic_load(tg + lane * 16, __ATOMIC_ACQUIRE,
                                __HIP_MEMORY_SCOPE_AGENT);
    }
    __syncthreads();   // B1

    // Z loads (plain cached, post-inv; slack until epilogue)
    const uint16_t* zt = Zb + (size_t)t * NB * NG;
    float2 vzi = zld2b(zt);
    float2 vzg = zld2b(zt + 512);
    float2 vzf = zld2b(zt + 1024);
    float2 vzo = zld2b(zt + 1536);

    // --- recurrent GEMM: gates_h = h @ Wh_panel ---
    const uint16_t* hA = hb + (t & 1) * NB * HH;
    const bool zr0 = (rm >> r0) & 1;
    const bool zr1 = (rm >> (16 + r0)) & 1;
    const int kof = khalf * 256 + k8;

    floatx4 acc[2][2];
#pragma unroll
    for (int m = 0; m < 2; ++m)
#pragma unroll
      for (int n = 0; n < 2; ++n)
#pragma unroll
        for (int r = 0; r < 4; ++r) acc[m][n][r] = 0.f;

#pragma unroll
    for (int kk = 0; kk < 8; ++kk) {
      short8 a0 = *(const short8*)(hA + (size_t)r0 * HH + kof + kk * 32);
      short8 a1 = *(const short8*)(hA + (size_t)(16 + r0) * HH + kof + kk * 32);
      if (zr0) a0 = zero8;               // ResetCore: h := 0 before step
      if (zr1) a1 = zero8;
      short8 b0 = *(const short8*)((const char*)sW + ((wrow0 + kk * 64) ^ swz));
      short8 b1 = *(const short8*)((const char*)sW + ((wrow1 + kk * 64) ^ swz));
      acc[0][0] = __builtin_amdgcn_mfma_f32_16x16x32_bf16(a0, b0, acc[0][0], 0, 0, 0);
      acc[0][1] = __builtin_amdgcn_mfma_f32_16x16x32_bf16(a0, b1, acc[0][1], 0, 0, 0);
      acc[1][0] = __builtin_amdgcn_mfma_f32_16x16x32_bf16(a1, b0, acc[1][0], 0, 0, 0);
      acc[1][1] = __builtin_amdgcn_mfma_f32_16x16x32_bf16(a1, b1, acc[1][1], 0, 0, 0);
    }

    // partial sums: khalf0 writes, khalf1 accumulates in place
    if (khalf == 0) {
#pragma unroll
      for (int m = 0; m < 2; ++m)
#pragma unroll
        for (int n = 0; n < 2; ++n)
#pragma unroll
          for (int r = 0; r < 4; ++r) {
            int row = m * 16 + (lane >> 4) * 4 + r;
            sG[row * 128 + gate * 32 + n * 16 + r0] = acc[m][n][r];
          }
    }
    __syncthreads();   // B2
    if (khalf == 1) {
#pragma unroll
      for (int m = 0; m < 2; ++m)
#pragma unroll
        for (int n = 0; n < 2; ++n)
#pragma unroll
          for (int r = 0; r < 4; ++r) {
            int row = m * 16 + (lane >> 4) * 4 + r;
            sG[row * 128 + gate * 32 + n * 16 + r0] += acc[m][n][r];
          }
    }
    __syncthreads();   // B3

    // --- epilogue: gate nonlinearities + state update (2 outputs/thread) ---
    const int gb = b_e * 128;
    const bool cz = (rm >> b_e) & 1;
    float hv0, hv1;
#pragma unroll
    for (int j = 0; j < 2; ++j) {
      int hc = hc0 + j;
      float xi = sG[gb + hc]      + (j ? vzi.y : vzi.x);
      float xg = sG[gb + 32 + hc] + (j ? vzg.y : vzg.x);
      float xf = sG[gb + 64 + hc] + (j ? vzf.y : vzf.x);
      float xo = sG[gb + 96 + hc] + (j ? vzo.y : vzo.x);
      float ii = fsigm(xi);
      float gg = ftanh(xg);
      float ff = fsigm(xf + 1.0f);   // haiku +1 forget-gate bias
      float oo = fsigm(xo);
      float cp = j ? cst1 : cst0;
      if (cz) cp = 0.f;              // ResetCore: c := 0 before step
      float cn = ff * cp + ii * gg;
      if (j) cst1 = cn; else cst0 = cn;
      float hn = oo * ftanh(cn);
      if (j) hv1 = hn; else hv0 = hn;
    }
    // publish bf16 h coherently (agent write-through)
    uint32_t hpack = (uint32_t)f2bf(hv0) | ((uint32_t)f2bf(hv1) << 16);
    __hip_atomic_store(
        (uint32_t*)(hb + ((t + 1) & 1) * NB * HH + (size_t)b_e * HH + p * 32 + hc0),
        hpack, __ATOMIC_RELAXED, __HIP_MEMORY_SCOPE_AGENT);

    asm volatile("s_waitcnt vmcnt(0)" ::: "memory");
    __syncthreads();   // B4: all h publishes drained before tag
    if (tid == 0)
      __hip_atomic_store(myslot, t + 1, __ATOMIC_RELAXED,
                         __HIP_MEMORY_SCOPE_AGENT);

    // fp32 output store AFTER the tag — HBM ack off the critical path
    const int t_x = dir ? (LSEQ - 1 - t) : t;
    float2 ov; ov.x = hv0; ov.y = hv1;
    *(float2*)(out + ((size_t)b_e * LSEQ + t_x) * 1024 + dir * 512 + p * 32 + hc0) = ov;
  }
}

// ---------------- diagnostic ----------------
__global__ void k_report(float* __restrict__ out, int n, float val)
{
  int tid = blockIdx.x * blockDim.x + threadIdx.x;
  int stride = gridDim.x * blockDim.x;
  for (int i = tid; i < n; i += stride) out[i] = val;
}

extern "C" void kernel_launch(void* const* d_in, const int* in_sizes, int n_in,
                              void* d_out, int out_size, void* d_ws, size_t ws_size,
                              hipStream_t stream)
{
  const float* x   = (const float*)d_in[0];
  const float* Wf  = (const float*)d_in[1];
  const float* bf_ = (const float*)d_in[2];
  const float* Wb  = (const float*)d_in[3];
  const float* bb_ = (const float*)d_in[4];
  const int*   len = (const int*)d_in[5];
  float* out = (float*)d_out;
  char* ws = (char*)d_ws;

  if (ws_size < WS_NEED) {
    k_report<<<2048, 256, 0, stream>>>(out, out_size,
                                       200.0f + (float)(ws_size >> 20) * 0.1f);
    return;
  }

  uint16_t* WX  = (uint16_t*)(ws + WX_OFF);
  uint16_t* WHp = (uint16_t*)(ws + WH_OFF);
  uint16_t* X   = (uint16_t*)(ws + X_OFF);
  uint16_t* H   = (uint16_t*)(ws + H_OFF);
  uint32_t* RST = (uint32_t*)(ws + RST_OFF);
  int*      TAG = (int*)(ws + TAG_OFF);
  int*      ZR  = (int*)(ws + ZR_OFF);
  uint16_t* Z   = (uint16_t*)(ws + Z_OFF);

  k_init<<<64, 256, 0, stream>>>(len, RST, TAG, ZR, H);
  k_wcast<<<4096, 256, 0, stream>>>(Wf, Wb, WX, WHp);
  k_xcast<<<16384, 256, 0, stream>>>(x, X);
  k_rec<<<256, 512, 0, stream>>>(WHp, WX, X, Z, bf_, bb_, RST, H, TAG, ZR, out);
}